// Round 16
// baseline (114.863 us; speedup 1.0000x reference)
//
#include <hip/hip_runtime.h>
#include <math.h>

// Problem constants
#define NXD 64
#define NYD 48
#define NZD 32
#define NPT (NXD*NYD*NZD)   // 98304 points
#define PN  10              // neighbors per point
#define MF  5               // fourier modes
#define H1  64
#define H2  32
#define H3  8

// R16: ONE-WAVE BLOCKS (64 threads), ZERO barriers. Each block: 4 chunks x 8 points
// (80 rows = 5 tiles of 16) -> grid 3072. All data (coords, obuf, tables) is private
// to the wave; same-wave LDS is in-order so no __syncthreads needed anywhere.
// Coord prefetch kept via counted s_waitcnt vmcnt(N) (never drain to 0).
// Rationale: R11-R15 falsified grid/VGPR/ILP/scheduler levers one by one; the 4-wave
// barrier lockstep (2 barriers/chunk, full waitcnt drain + rendezvous of latency-skewed
// waves) is the last untouched structural suppressor of wave slip.
#define CHUNKS 4
#define PTS_PER_CHUNK 8
#define ROWS_PER_CHUNK (PTS_PER_CHUNK*PN)   // 80
#define TILES_PER_CHUNK 5

#define INV2PI 0.15915494309189535f

typedef __attribute__((ext_vector_type(8))) _Float16 half8;   // 8 f16 = 4 VGPRs
typedef __attribute__((ext_vector_type(2))) _Float16 half2v;
typedef __attribute__((ext_vector_type(2))) __fp16   fp16x2;  // cvt_pkrtz return type
typedef __attribute__((ext_vector_type(2))) short    shortv2;
typedef __attribute__((ext_vector_type(4))) float    f32x4;

// pack two f32 -> half2v via v_cvt_pkrtz_f16_f32 (1 instr)
__device__ __forceinline__ half2v cvt_pk_h2(float lo, float hi) {
    fp16x2 p = __builtin_amdgcn_cvt_pkrtz(lo, hi);
    return __builtin_bit_cast(half2v, p);
}

// Per-(lg,j) feature descriptor for the PERMUTED K-ordering of layer 1.
//   lg0: [x,   s0x,s1x,s2x,s3x,s4x, c0x,c1x]            (cA=x, cB=x)
//   lg1: [y,   c2x,c3x,c4x, s0y,s1y,s2y,s3y]            (cA=x, cB=y)
//   lg2: [z,   s4y, c0y,c1y,c2y,c3y,c4y, s0z]           (cA=y, cB=z)
//   lg3: [s1z,s2z,s3z,s4z, c0z,c1z,c2z,c3z]             (cA=z, cB=z)
// leftover channel 32 = c4z (rank-1 fixup).
// encoding: row(6b) | m(3b)<<6 | path(1b)<<9 | type(2b)<<10  (0=sin,1=cos,2=raw)
static __device__ const unsigned short kSlotTab[32] = {
  2048,    3,   70,  137,  204,  271, 1042, 1109,   // lg0
  2561, 1176, 1243, 1310,  516,  583,  650,  717,   // lg1
  2562,  272, 1043, 1110, 1177, 1244, 1311,  517,   // lg2
    72,  139,  206,  273, 1044, 1111, 1178, 1245 }; // lg3

// hardware f16 exp2 (trans pipe, 1 instr) — used only by tanh
__device__ __forceinline__ _Float16 exp2h(_Float16 v) {
    _Float16 r;
    asm("v_exp_f16 %0, %1" : "=v"(r) : "v"(v));
    return r;
}

#define H2C(v) ((half2v){(_Float16)(v), (_Float16)(v)})

// TRANSCENDENTAL-FREE packed-f16 GELU on a pair of f32 pre-activations.
// gelu(x) = 0.5x(1 + erf(x/sqrt2)), erf approx = x*q(x^2), q quintic in u=x^2/4,
// nodes x in {0,1,2,2.5,3,3.4}; clamp th=x/2 to +-1.7. ~3e-4 err. 12 VALU, 0 trans.
__device__ __forceinline__ half2v gelu_pk(float lo, float hi) {
    const half2v x  = cvt_pk_h2(lo, hi);
    const half2v hx = x * H2C(0.5f);
    half2v th = __builtin_elementwise_max(hx, H2C(-1.7f));
    th = __builtin_elementwise_min(th, H2C(1.7f));
    const half2v u = th * th;                       // x^2/4, <= 2.89
    half2v h = __builtin_elementwise_fma(u, H2C(-0.0026649190f), H2C(0.027104255f));
    h = __builtin_elementwise_fma(u, h, H2C(-0.11827712f));
    h = __builtin_elementwise_fma(u, h, H2C(0.30261872f));
    h = __builtin_elementwise_fma(u, h, H2C(-0.52941544f));
    h = __builtin_elementwise_fma(u, h, H2C(0.797885f));
    const half2v w = th * h;
    return __builtin_elementwise_fma(x, w, hx);
}

// Packed-f16 tanh*mask: tanh = 1 - 2/(1+2^{2*log2e*v}); rcp via f16 bit-trick
// (0x7800 - bits(y)) + 2 Newton. t<=14 keeps y normal; t->-inf -> tanh=-1 exact.
__device__ __forceinline__ half2v tanh_pk_masked(float lo, float hi, half2v mkh) {
    half2v t = cvt_pk_h2(lo, hi) * H2C(2.8853901f);
    t = __builtin_elementwise_min(t, H2C(14.0f));
    const _Float16 e0 = exp2h(t[0]);
    const _Float16 e1 = exp2h(t[1]);
    const half2v y = (half2v){e0, e1} + H2C(1.0f);
    const shortv2 rb = (shortv2){(short)0x7800, (short)0x7800} - __builtin_bit_cast(shortv2, y);
    half2v r = __builtin_bit_cast(half2v, rb);
    r = r * __builtin_elementwise_fma(-y, r, H2C(2.0f));
    r = r * __builtin_elementwise_fma(-y, r, H2C(2.0f));
    const half2v th = __builtin_elementwise_fma(r, H2C(-2.0f), H2C(1.0f));
    return th * mkh;
}

__global__ __launch_bounds__(64) void domino_mfma_kernel(
    const float* __restrict__ x,      // (NPT*PN, 3)
    const float* __restrict__ freqs,  // (MF,)
    const float* __restrict__ W1,     // (33, 64)
    const float* __restrict__ b1,
    const float* __restrict__ W2,     // (64, 32)
    const float* __restrict__ b2,
    const float* __restrict__ W3,     // (32, 8)
    const float* __restrict__ b3,
    float* __restrict__ out)          // (8, NPT)
{
    // Per-block LDS ~5.5 KB -> many 1-wave workgroups pack per CU:
    __shared__ __align__(16) float cbuf[2][256];                  // 2048 B coords (80 rows + slack)
    __shared__ __align__(16) _Float16 obuf[ROWS_PER_CHUNK * 10];  // 1600 B masked tanh rows
    __shared__ __align__(16) float coefA[32];                     // 384 B coef tables
    __shared__ __align__(16) float coefB[32];
    __shared__ __align__(16) float coefO[32];
    // bias/fixup: [copy][lg][ 0..15 bv1 | 16..31 w32 | 32..39 bv2 | 40..43 bv3 ]
    __shared__ __align__(16) float biasT[2][4][44];               // 1408 B

    const int lane = threadIdx.x;   // 0..63 (whole block = 1 wave)
    const int lr   = lane & 15;     // point index (n-col of swapped MFMA)
    const int lg   = lane >> 4;     // k-group / channel-row group

    // ---- coord staging: one global_load_lds dwordx4 per chunk (960 B used, 1024 B
    // written; rows 80..85 land in cbuf slack, never read). Clamp only the global
    // tail of the very last chunk (lanes 60-63 would read past x's end).
    auto stage_coords = [&](int c, int buf) {
        const int row0 = (blockIdx.x*CHUNKS + c) * ROWS_PER_CHUNK;
        const int sl = (row0 + ROWS_PER_CHUNK == NPT*PN && lane >= 60) ? 59 : lane;
        const float* gsrc = x + (size_t)row0 * 3 + (size_t)sl * 4;
        __builtin_amdgcn_global_load_lds(
            (const __attribute__((address_space(1))) void*)gsrc,
            (__attribute__((address_space(3))) void*)&cbuf[buf][0], 16, 0, 0);
    };

    // ---- fill per-lg coefficient tables (lanes 0..31; same-wave LDS is in-order,
    // so later reads by all 64 lanes need no barrier)
    if (lane < 32) {
        const unsigned e = kSlotTab[lane];
        const int m = (e >> 6) & 7, path = (e >> 9) & 1, ty = (e >> 10) & 3;
        const float fm = freqs[m] * INV2PI;
        coefA[lane] = (ty != 2 && path == 0) ? fm : 0.0f;
        coefB[lane] = (ty != 2 && path == 1) ? fm : 0.0f;
        coefO[lane] = (ty == 1) ? 0.25f : 0.0f;
    }

    // ---- fill bias/fixup table (4 lanes: lr==0, one per lg)
    if (lr == 0) {
        #pragma unroll
        for (int t1 = 0; t1 < 4; ++t1)
            #pragma unroll
            for (int r = 0; r < 4; ++r) {
                const float bv = b1[t1*16 + lg*4 + r];
                const float wv = W1[32*H1 + t1*16 + lg*4 + r];
                biasT[0][lg][t1*4 + r] = bv;      biasT[1][lg][t1*4 + r] = bv;
                biasT[0][lg][16 + t1*4 + r] = wv; biasT[1][lg][16 + t1*4 + r] = wv;
            }
        #pragma unroll
        for (int t2 = 0; t2 < 2; ++t2)
            #pragma unroll
            for (int r = 0; r < 4; ++r) {
                const float bv = b2[t2*16 + lg*4 + r];
                biasT[0][lg][32 + t2*4 + r] = bv; biasT[1][lg][32 + t2*4 + r] = bv;
            }
        #pragma unroll
        for (int r = 0; r < 4; ++r) {
            const float bv = (lg < 2) ? b3[lg*4 + r] : 0.0f;
            biasT[0][lg][40 + r] = bv; biasT[1][lg][40 + r] = bv;
        }
    }

    stage_coords(0, 0);   // chunk-0 coords overlap the weight prologue below

    const float f4rev = freqs[4] * INV2PI;
    const float rawf  = (lg < 3) ? 1.0f : 0.0f;   // slot0 is a raw coordinate for lg0..2

    // ---- weight fragments for SWAPPED mfma (W as A-operand: m=lane&15=out-channel).
    half8 B1f[4];
    #pragma unroll
    for (int t1 = 0; t1 < 4; ++t1)
        #pragma unroll
        for (int j = 0; j < 8; ++j) {
            const int row = kSlotTab[lg*8 + j] & 63;
            B1f[t1][j] = (_Float16)W1[row*H1 + t1*16 + lr];
        }
    // Layer2: pi2(q,s,j) = (2q+(j>>2))*16 + 4s + (j&3)
    half8 B2f[2][2];
    #pragma unroll
    for (int q = 0; q < 2; ++q)
        #pragma unroll
        for (int t2 = 0; t2 < 2; ++t2)
            #pragma unroll
            for (int j = 0; j < 8; ++j)
                B2f[q][t2][j] = (_Float16)W2[((2*q + (j>>2))*16 + lg*4 + (j&3))*H2 + t2*16 + lr];
    // Layer3: pi3(s,j) = (j>>2)*16 + 4s + (j&3)
    half8 B3f;
    #pragma unroll
    for (int j = 0; j < 8; ++j)
        B3f[j] = (lr < H3) ? (_Float16)W3[((j>>2)*16 + lg*4 + (j&3))*H3 + lr] : (_Float16)0.0f;

    // ---- coefficient vectors hoisted to registers (reads ordered after the LDS
    // writes above by same-wave program order; compiler inserts the lgkmcnt)
    const f32x4 fa0 = *(const f32x4*)&coefA[lg*8];
    const f32x4 fb0 = *(const f32x4*)&coefB[lg*8];
    const f32x4 fo0 = *(const f32x4*)&coefO[lg*8];
    const f32x4 fa1 = *(const f32x4*)&coefA[lg*8 + 4];
    const f32x4 fb1 = *(const f32x4*)&coefB[lg*8 + 4];
    const f32x4 fo1 = *(const f32x4*)&coefO[lg*8 + 4];

    // ================= chunk loop (NO barriers) =================
    #pragma unroll 1
    for (int c = 0; c < CHUNKS; ++c) {
        if (c + 1 < CHUNKS) stage_coords(c + 1, (c + 1) & 1);  // prefetch next chunk

        // Counted vmcnt: retire stage(c) while letting the newest ops fly.
        // Outstanding ledger at this point (issue order, oldest first):
        //   c==0:            [stage(0), stage(1)]                 -> vmcnt(1)
        //   0<c<CHUNKS-1:    [.., stage(c), store(c-1), stage(c+1)] -> vmcnt(2)
        //   c==CHUNKS-1:     [stage(c), store(c-1)]               -> vmcnt(1)
        if (c == 0 || c + 1 == CHUNKS) asm volatile("s_waitcnt vmcnt(1)" ::: "memory");
        else                           asm volatile("s_waitcnt vmcnt(2)" ::: "memory");
        __builtin_amdgcn_sched_barrier(0);

        const float* cbp = &cbuf[c & 1][0];

        // ---- tile loop: straight-line; scheduler overlaps adjacent tiles' chains
        #pragma unroll
        for (int t = 0; t < TILES_PER_CHUNK; ++t) {
            const float* bT = &biasT[t & 1][lg][0];

            // ---- coords of point lr (4 lane-groups broadcast)
            const int cfx = (t*16 + lr)*3;
            const float cx = cbp[cfx + 0];
            const float cy = cbp[cfx + 1];
            const float cz = cbp[cfx + 2];
            const float cA = (lg <= 1) ? cx : ((lg == 2) ? cy : cz);
            const float cB = (lg == 0) ? cx : ((lg == 1) ? cy : cz);

            // ---- 8 features + ch32: 2 fma + fract + v_sin each
            float f0 = __builtin_amdgcn_sinf(__builtin_amdgcn_fractf(cA*fa0[0] + (cB*fb0[0] + fo0[0])));
            float f1 = __builtin_amdgcn_sinf(__builtin_amdgcn_fractf(cA*fa0[1] + (cB*fb0[1] + fo0[1])));
            float f2 = __builtin_amdgcn_sinf(__builtin_amdgcn_fractf(cA*fa0[2] + (cB*fb0[2] + fo0[2])));
            float f3 = __builtin_amdgcn_sinf(__builtin_amdgcn_fractf(cA*fa0[3] + (cB*fb0[3] + fo0[3])));
            float f4 = __builtin_amdgcn_sinf(__builtin_amdgcn_fractf(cA*fa1[0] + (cB*fb1[0] + fo1[0])));
            float f5 = __builtin_amdgcn_sinf(__builtin_amdgcn_fractf(cA*fa1[1] + (cB*fb1[1] + fo1[1])));
            float f6 = __builtin_amdgcn_sinf(__builtin_amdgcn_fractf(cA*fa1[2] + (cB*fb1[2] + fo1[2])));
            float f7 = __builtin_amdgcn_sinf(__builtin_amdgcn_fractf(cA*fa1[3] + (cB*fb1[3] + fo1[3])));
            f0 += rawf * (cB - f0);   // slot0 raw-coordinate override (no-op lg3)
            const float v32 = __builtin_amdgcn_sinf(__builtin_amdgcn_fractf(cz * f4rev + 0.25f));

            union { half2v h2[4]; half8 h8; } a1u;
            a1u.h2[0] = cvt_pk_h2(f0, f1);
            a1u.h2[1] = cvt_pk_h2(f2, f3);
            a1u.h2[2] = cvt_pk_h2(f4, f5);
            a1u.h2[3] = cvt_pk_h2(f6, f7);
            const half8 a1 = a1u.h8;

            // ---- Layer 1 SWAPPED: bias C-init from LDS; ch32 rank-1 fixup from LDS
            f32x4 c1[4];
            #pragma unroll
            for (int t1 = 0; t1 < 4; ++t1)
                c1[t1] = __builtin_amdgcn_mfma_f32_16x16x32_f16(B1f[t1], a1, *(const f32x4*)&bT[t1*4], 0, 0, 0);
            #pragma unroll
            for (int t1 = 0; t1 < 4; ++t1) {
                const f32x4 wv = *(const f32x4*)&bT[16 + t1*4];
                #pragma unroll
                for (int r = 0; r < 4; ++r)
                    c1[t1][r] += v32 * wv[r];
            }

            // ---- gelu + pack IN REGISTERS (pi2 ordering)
            union { half2v h2[4]; half8 h8; } a2u0, a2u1;
            a2u0.h2[0] = gelu_pk(c1[0][0], c1[0][1]);
            a2u0.h2[1] = gelu_pk(c1[0][2], c1[0][3]);
            a2u0.h2[2] = gelu_pk(c1[1][0], c1[1][1]);
            a2u0.h2[3] = gelu_pk(c1[1][2], c1[1][3]);
            a2u1.h2[0] = gelu_pk(c1[2][0], c1[2][1]);
            a2u1.h2[1] = gelu_pk(c1[2][2], c1[2][3]);
            a2u1.h2[2] = gelu_pk(c1[3][0], c1[3][1]);
            a2u1.h2[3] = gelu_pk(c1[3][2], c1[3][3]);

            // ---- Layer 2 SWAPPED: K=64 via 2 q-steps; bias C-init from LDS
            f32x4 c2[2];
            #pragma unroll
            for (int t2 = 0; t2 < 2; ++t2) {
                f32x4 ci = __builtin_amdgcn_mfma_f32_16x16x32_f16(B2f[0][t2], a2u0.h8, *(const f32x4*)&bT[32 + t2*4], 0, 0, 0);
                c2[t2]   = __builtin_amdgcn_mfma_f32_16x16x32_f16(B2f[1][t2], a2u1.h8, ci, 0, 0, 0);
            }

            // ---- gelu + pack (pi3 ordering)
            union { half2v h2[4]; half8 h8; } a3u;
            a3u.h2[0] = gelu_pk(c2[0][0], c2[0][1]);
            a3u.h2[1] = gelu_pk(c2[0][2], c2[0][3]);
            a3u.h2[2] = gelu_pk(c2[1][0], c2[1][1]);
            a3u.h2[3] = gelu_pk(c2[1][2], c2[1][3]);

            // ---- Layer 3 SWAPPED + tanh + mask + store
            f32x4 c3 = __builtin_amdgcn_mfma_f32_16x16x32_f16(B3f, a3u.h8, *(const f32x4*)&bT[40], 0, 0, 0);
            const float mk = (fabsf(cx) > 1e-6f) ? 1.0f : 0.0f;
            const half2v mkh = cvt_pk_h2(mk, mk);
            const half2v t01 = tanh_pk_masked(c3[0], c3[1], mkh);
            const half2v t23 = tanh_pk_masked(c3[2], c3[3], mkh);
            if (lg < 2) {
                const int base = (t*16 + lr)*10 + lg*4;
                *(half2v*)&obuf[base]     = t01;
                *(half2v*)&obuf[base + 2] = t23;
            }
        }

        // ---- neighbor reduction: 8 points x 8 channels = 64 lanes. Same-wave LDS
        // is in-order, so obuf writes above are visible with no barrier.
        {
            const int p  = lane >> 3;   // 0..7
            const int ch = lane & 7;
            float sum = 0.0f;
            #pragma unroll
            for (int i = 0; i < PN; ++i) sum += (float)obuf[(p*PN + i)*10 + ch];
            const int gp = blockIdx.x * (PTS_PER_CHUNK*CHUNKS) + c*PTS_PER_CHUNK + p;
            out[(size_t)ch * NPT + gp] = sum;
        }
        // obuf reuse next chunk is safe: these reads complete (results consumed by
        // the store) before the next chunk's ds_writes issue — same-wave in-order.
    }
}

extern "C" void kernel_launch(void* const* d_in, const int* in_sizes, int n_in,
                              void* d_out, int out_size, void* d_ws, size_t ws_size,
                              hipStream_t stream) {
    // setup_inputs order: x, grid(unused), freqs, W1, b1, W2, b2, W3, b3
    const float* x     = (const float*)d_in[0];
    const float* freqs = (const float*)d_in[2];
    const float* W1    = (const float*)d_in[3];
    const float* b1    = (const float*)d_in[4];
    const float* W2    = (const float*)d_in[5];
    const float* b2    = (const float*)d_in[6];
    const float* W3    = (const float*)d_in[7];
    const float* b3    = (const float*)d_in[8];
    float* out = (float*)d_out;

    const int grid = NPT / (PTS_PER_CHUNK * CHUNKS);   // 3072 blocks, no remainder
    domino_mfma_kernel<<<grid, 64, 0, stream>>>(x, freqs, W1, b1, W2, b2, W3, b3, out);
}

// Round 17
// 111.962 us; speedup vs baseline: 1.0259x; 1.0259x over previous
//
#include <hip/hip_runtime.h>
#include <math.h>

// Problem constants
#define NXD 64
#define NYD 48
#define NZD 32
#define NPT (NXD*NYD*NZD)   // 98304 points
#define PN  10              // neighbors per point
#define MF  5               // fourier modes
#define H1  64
#define H2  32
#define H3  8

// FINAL: R15 structure (best measured band 47.4-47.6 us) + biasT single-copy so the
// compiler hoists bias/fixup vectors into registers across the unrolled tile body.
// Session ledger: work-reduction won (feature dedup, f16 datapath, 0-trans GELU,
// algebraic de-transposing); ALL latency/occupancy levers individually null
// (grid 768/1536/3072, waves 3k/6k/12k, VGPR 52-80, pairing, unroll, 0-barrier).
// NO __launch_bounds__ min-waves (R12: pinning starved allocator -> spills).
#define PTS_PER_BLOCK 32
#define CHUNKS 2
#define ROWS_PER_BLOCK (PTS_PER_BLOCK*PN)   // 320 per chunk
#define TILES_PER_WAVE 5

#define INV2PI 0.15915494309189535f

typedef __attribute__((ext_vector_type(8))) _Float16 half8;   // 8 f16 = 4 VGPRs
typedef __attribute__((ext_vector_type(2))) _Float16 half2v;
typedef __attribute__((ext_vector_type(2))) __fp16   fp16x2;  // cvt_pkrtz return type
typedef __attribute__((ext_vector_type(2))) short    shortv2;
typedef __attribute__((ext_vector_type(4))) float    f32x4;

// pack two f32 -> half2v via v_cvt_pkrtz_f16_f32 (1 instr)
__device__ __forceinline__ half2v cvt_pk_h2(float lo, float hi) {
    fp16x2 p = __builtin_amdgcn_cvt_pkrtz(lo, hi);
    return __builtin_bit_cast(half2v, p);
}

// Per-(lg,j) feature descriptor for the PERMUTED K-ordering of layer 1.
//   lg0: [x,   s0x,s1x,s2x,s3x,s4x, c0x,c1x]            (cA=x, cB=x)
//   lg1: [y,   c2x,c3x,c4x, s0y,s1y,s2y,s3y]            (cA=x, cB=y)
//   lg2: [z,   s4y, c0y,c1y,c2y,c3y,c4y, s0z]           (cA=y, cB=z)
//   lg3: [s1z,s2z,s3z,s4z, c0z,c1z,c2z,c3z]             (cA=z, cB=z)
// leftover channel 32 = c4z (rank-1 fixup).
// encoding: row(6b) | m(3b)<<6 | path(1b)<<9 | type(2b)<<10  (0=sin,1=cos,2=raw)
static __device__ const unsigned short kSlotTab[32] = {
  2048,    3,   70,  137,  204,  271, 1042, 1109,   // lg0
  2561, 1176, 1243, 1310,  516,  583,  650,  717,   // lg1
  2562,  272, 1043, 1110, 1177, 1244, 1311,  517,   // lg2
    72,  139,  206,  273, 1044, 1111, 1178, 1245 }; // lg3

// hardware f16 exp2 (trans pipe, 1 instr) — used only by tanh
__device__ __forceinline__ _Float16 exp2h(_Float16 v) {
    _Float16 r;
    asm("v_exp_f16 %0, %1" : "=v"(r) : "v"(v));
    return r;
}

#define H2C(v) ((half2v){(_Float16)(v), (_Float16)(v)})

// TRANSCENDENTAL-FREE packed-f16 GELU on a pair of f32 pre-activations.
// gelu(x) = 0.5x(1 + erf(x/sqrt2)), erf approx = x*q(x^2), q quintic in u=x^2/4,
// nodes x in {0,1,2,2.5,3,3.4}; clamp th=x/2 to +-1.7. ~3e-4 err. 12 VALU, 0 trans.
__device__ __forceinline__ half2v gelu_pk(float lo, float hi) {
    const half2v x  = cvt_pk_h2(lo, hi);
    const half2v hx = x * H2C(0.5f);
    half2v th = __builtin_elementwise_max(hx, H2C(-1.7f));
    th = __builtin_elementwise_min(th, H2C(1.7f));
    const half2v u = th * th;                       // x^2/4, <= 2.89
    half2v h = __builtin_elementwise_fma(u, H2C(-0.0026649190f), H2C(0.027104255f));
    h = __builtin_elementwise_fma(u, h, H2C(-0.11827712f));
    h = __builtin_elementwise_fma(u, h, H2C(0.30261872f));
    h = __builtin_elementwise_fma(u, h, H2C(-0.52941544f));
    h = __builtin_elementwise_fma(u, h, H2C(0.797885f));
    const half2v w = th * h;
    return __builtin_elementwise_fma(x, w, hx);
}

// Packed-f16 tanh*mask: tanh = 1 - 2/(1+2^{2*log2e*v}); rcp via f16 bit-trick
// (0x7800 - bits(y)) + 2 Newton. t<=14 keeps y normal; t->-inf -> tanh=-1 exact.
__device__ __forceinline__ half2v tanh_pk_masked(float lo, float hi, half2v mkh) {
    half2v t = cvt_pk_h2(lo, hi) * H2C(2.8853901f);
    t = __builtin_elementwise_min(t, H2C(14.0f));
    const _Float16 e0 = exp2h(t[0]);
    const _Float16 e1 = exp2h(t[1]);
    const half2v y = (half2v){e0, e1} + H2C(1.0f);
    const shortv2 rb = (shortv2){(short)0x7800, (short)0x7800} - __builtin_bit_cast(shortv2, y);
    half2v r = __builtin_bit_cast(half2v, rb);
    r = r * __builtin_elementwise_fma(-y, r, H2C(2.0f));
    r = r * __builtin_elementwise_fma(-y, r, H2C(2.0f));
    const half2v th = __builtin_elementwise_fma(r, H2C(-2.0f), H2C(1.0f));
    return th * mkh;
}

__global__ __launch_bounds__(256) void domino_mfma_kernel(
    const float* __restrict__ x,      // (NPT*PN, 3)
    const float* __restrict__ freqs,  // (MF,)
    const float* __restrict__ W1,     // (33, 64)
    const float* __restrict__ b1,
    const float* __restrict__ W2,     // (64, 32)
    const float* __restrict__ b2,
    const float* __restrict__ W3,     // (32, 8)
    const float* __restrict__ b3,
    float* __restrict__ out)          // (8, NPT)
{
    // LDS budget ~15.5 KB:
    __shared__ __align__(16) float cbuf[2][976];                 // 7808 B staged coords (dbuf)
    __shared__ __align__(16) _Float16 obuf[ROWS_PER_BLOCK * 10]; // 6400 B masked tanh rows
    __shared__ __align__(16) float coefA[32];                    // 384 B coef tables
    __shared__ __align__(16) float coefB[32];
    __shared__ __align__(16) float coefO[32];
    // bias/fixup table (SINGLE copy — loop-invariant addr lets the compiler hoist
    // these 11 f32x4 vectors into registers across the unrolled 5-tile body):
    // [lg][ 0..15 bv1(t1*4+r) | 16..31 w32 | 32..39 bv2 | 40..43 bv3 ]
    __shared__ __align__(16) float biasT[4][44];                 // 704 B

    const int tid  = threadIdx.x;
    const int w    = tid >> 6;      // wave id 0..3
    const int lane = tid & 63;
    const int lr   = lane & 15;     // point index (n-col of swapped MFMA)
    const int lg   = lane >> 4;     // k-group / channel-row group

    // ---- coord staging: one global_load_lds dwordx4 per wave per chunk (960 B).
    auto stage_coords = [&](int c, int buf) {
        const int row0 = (blockIdx.x*CHUNKS + c) * ROWS_PER_BLOCK + w*(TILES_PER_WAVE*16);
        const int sl = (w == 3 && lane >= 60) ? 59 : lane;
        const float* gsrc = x + (size_t)row0 * 3 + (size_t)sl * 4;
        __builtin_amdgcn_global_load_lds(
            (const __attribute__((address_space(1))) void*)gsrc,
            (__attribute__((address_space(3))) void*)&cbuf[buf][w * 240], 16, 0, 0);
    };

    // ---- fill per-lg coefficient tables (32 threads; single copy — register-
    // hoisted per wave after the barrier)
    if (tid < 32) {
        const unsigned e = kSlotTab[tid];
        const int m = (e >> 6) & 7, path = (e >> 9) & 1, ty = (e >> 10) & 3;
        const float fm = freqs[m] * INV2PI;
        coefA[tid] = (ty != 2 && path == 0) ? fm : 0.0f;
        coefB[tid] = (ty != 2 && path == 1) ? fm : 0.0f;
        coefO[tid] = (ty == 1) ? 0.25f : 0.0f;
    }

    // ---- fill bias/fixup table (4 lanes: w==0, lr==0, one per lg)
    if (w == 0 && lr == 0) {
        #pragma unroll
        for (int t1 = 0; t1 < 4; ++t1)
            #pragma unroll
            for (int r = 0; r < 4; ++r) {
                biasT[lg][t1*4 + r]      = b1[t1*16 + lg*4 + r];
                biasT[lg][16 + t1*4 + r] = W1[32*H1 + t1*16 + lg*4 + r];
            }
        #pragma unroll
        for (int t2 = 0; t2 < 2; ++t2)
            #pragma unroll
            for (int r = 0; r < 4; ++r)
                biasT[lg][32 + t2*4 + r] = b2[t2*16 + lg*4 + r];
        #pragma unroll
        for (int r = 0; r < 4; ++r)
            biasT[lg][40 + r] = (lg < 2) ? b3[lg*4 + r] : 0.0f;
    }

    stage_coords(0, 0);   // chunk 0 coords overlap the weight prologue below

    const float f4rev = freqs[4] * INV2PI;
    const float rawf  = (lg < 3) ? 1.0f : 0.0f;   // slot0 is a raw coordinate for lg0..2

    // ---- weight fragments for SWAPPED mfma (W as A-operand: m=lane&15=out-channel).
    half8 B1f[4];
    #pragma unroll
    for (int t1 = 0; t1 < 4; ++t1)
        #pragma unroll
        for (int j = 0; j < 8; ++j) {
            const int row = kSlotTab[lg*8 + j] & 63;
            B1f[t1][j] = (_Float16)W1[row*H1 + t1*16 + lr];
        }
    // Layer2: pi2(q,s,j) = (2q+(j>>2))*16 + 4s + (j&3)
    half8 B2f[2][2];
    #pragma unroll
    for (int q = 0; q < 2; ++q)
        #pragma unroll
        for (int t2 = 0; t2 < 2; ++t2)
            #pragma unroll
            for (int j = 0; j < 8; ++j)
                B2f[q][t2][j] = (_Float16)W2[((2*q + (j>>2))*16 + lg*4 + (j&3))*H2 + t2*16 + lr];
    // Layer3: pi3(s,j) = (j>>2)*16 + 4s + (j&3)
    half8 B3f;
    #pragma unroll
    for (int j = 0; j < 8; ++j)
        B3f[j] = (lr < H3) ? (_Float16)W3[((j>>2)*16 + lg*4 + (j&3))*H3 + lr] : (_Float16)0.0f;

    // tables + chunk-0 coords visible (implies vmcnt/lgkmcnt drain)
    __syncthreads();

    // ---- coefficient vectors: loaded ONCE into registers
    const f32x4 fa0 = *(const f32x4*)&coefA[lg*8];
    const f32x4 fb0 = *(const f32x4*)&coefB[lg*8];
    const f32x4 fo0 = *(const f32x4*)&coefO[lg*8];
    const f32x4 fa1 = *(const f32x4*)&coefA[lg*8 + 4];
    const f32x4 fb1 = *(const f32x4*)&coefB[lg*8 + 4];
    const f32x4 fo1 = *(const f32x4*)&coefO[lg*8 + 4];
    const float* bT = &biasT[lg][0];   // loop-invariant: loads CSE/hoist to registers

    // ================= chunk loop =================
    #pragma unroll 1
    for (int c = 0; c < CHUNKS; ++c) {
        if (c + 1 < CHUNKS) stage_coords(c + 1, (c + 1) & 1);  // hides under this chunk
        const float* cbp = &cbuf[c & 1][0];

        // ---- tile loop: fully unrolled straight line; scheduler overlaps adjacent
        // tiles' chain-entry latency with prior tiles' gelu/MFMA tails.
        #pragma unroll
        for (int t = 0; t < TILES_PER_WAVE; ++t) {
            // ---- coords of point lr (4 lane-groups broadcast)
            const int cfx = w*240 + (t*16 + lr)*3;
            const float cx = cbp[cfx + 0];
            const float cy = cbp[cfx + 1];
            const float cz = cbp[cfx + 2];
            const float cA = (lg <= 1) ? cx : ((lg == 2) ? cy : cz);
            const float cB = (lg == 0) ? cx : ((lg == 1) ? cy : cz);

            // ---- 8 features + ch32: 2 fma + fract + v_sin each
            float f0 = __builtin_amdgcn_sinf(__builtin_amdgcn_fractf(cA*fa0[0] + (cB*fb0[0] + fo0[0])));
            float f1 = __builtin_amdgcn_sinf(__builtin_amdgcn_fractf(cA*fa0[1] + (cB*fb0[1] + fo0[1])));
            float f2 = __builtin_amdgcn_sinf(__builtin_amdgcn_fractf(cA*fa0[2] + (cB*fb0[2] + fo0[2])));
            float f3 = __builtin_amdgcn_sinf(__builtin_amdgcn_fractf(cA*fa0[3] + (cB*fb0[3] + fo0[3])));
            float f4 = __builtin_amdgcn_sinf(__builtin_amdgcn_fractf(cA*fa1[0] + (cB*fb1[0] + fo1[0])));
            float f5 = __builtin_amdgcn_sinf(__builtin_amdgcn_fractf(cA*fa1[1] + (cB*fb1[1] + fo1[1])));
            float f6 = __builtin_amdgcn_sinf(__builtin_amdgcn_fractf(cA*fa1[2] + (cB*fb1[2] + fo1[2])));
            float f7 = __builtin_amdgcn_sinf(__builtin_amdgcn_fractf(cA*fa1[3] + (cB*fb1[3] + fo1[3])));
            f0 += rawf * (cB - f0);   // slot0 raw-coordinate override (no-op lg3)
            const float v32 = __builtin_amdgcn_sinf(__builtin_amdgcn_fractf(cz * f4rev + 0.25f));

            union { half2v h2[4]; half8 h8; } a1u;
            a1u.h2[0] = cvt_pk_h2(f0, f1);
            a1u.h2[1] = cvt_pk_h2(f2, f3);
            a1u.h2[2] = cvt_pk_h2(f4, f5);
            a1u.h2[3] = cvt_pk_h2(f6, f7);
            const half8 a1 = a1u.h8;

            // ---- Layer 1 SWAPPED: bias C-init; ch32 rank-1 fixup (hoisted vectors)
            f32x4 c1[4];
            #pragma unroll
            for (int t1 = 0; t1 < 4; ++t1)
                c1[t1] = __builtin_amdgcn_mfma_f32_16x16x32_f16(B1f[t1], a1, *(const f32x4*)&bT[t1*4], 0, 0, 0);
            #pragma unroll
            for (int t1 = 0; t1 < 4; ++t1) {
                const f32x4 wv = *(const f32x4*)&bT[16 + t1*4];
                #pragma unroll
                for (int r = 0; r < 4; ++r)
                    c1[t1][r] += v32 * wv[r];
            }

            // ---- gelu + pack IN REGISTERS (pi2 ordering)
            union { half2v h2[4]; half8 h8; } a2u0, a2u1;
            a2u0.h2[0] = gelu_pk(c1[0][0], c1[0][1]);
            a2u0.h2[1] = gelu_pk(c1[0][2], c1[0][3]);
            a2u0.h2[2] = gelu_pk(c1[1][0], c1[1][1]);
            a2u0.h2[3] = gelu_pk(c1[1][2], c1[1][3]);
            a2u1.h2[0] = gelu_pk(c1[2][0], c1[2][1]);
            a2u1.h2[1] = gelu_pk(c1[2][2], c1[2][3]);
            a2u1.h2[2] = gelu_pk(c1[3][0], c1[3][1]);
            a2u1.h2[3] = gelu_pk(c1[3][2], c1[3][3]);

            // ---- Layer 2 SWAPPED: K=64 via 2 q-steps
            f32x4 c2[2];
            #pragma unroll
            for (int t2 = 0; t2 < 2; ++t2) {
                f32x4 ci = __builtin_amdgcn_mfma_f32_16x16x32_f16(B2f[0][t2], a2u0.h8, *(const f32x4*)&bT[32 + t2*4], 0, 0, 0);
                c2[t2]   = __builtin_amdgcn_mfma_f32_16x16x32_f16(B2f[1][t2], a2u1.h8, ci, 0, 0, 0);
            }

            // ---- gelu + pack (pi3 ordering)
            union { half2v h2[4]; half8 h8; } a3u;
            a3u.h2[0] = gelu_pk(c2[0][0], c2[0][1]);
            a3u.h2[1] = gelu_pk(c2[0][2], c2[0][3]);
            a3u.h2[2] = gelu_pk(c2[1][0], c2[1][1]);
            a3u.h2[3] = gelu_pk(c2[1][2], c2[1][3]);

            // ---- Layer 3 SWAPPED + tanh + mask + store
            f32x4 c3 = __builtin_amdgcn_mfma_f32_16x16x32_f16(B3f, a3u.h8, *(const f32x4*)&bT[40], 0, 0, 0);
            const float mk = (fabsf(cx) > 1e-6f) ? 1.0f : 0.0f;
            const half2v mkh = cvt_pk_h2(mk, mk);
            const half2v t01 = tanh_pk_masked(c3[0], c3[1], mkh);
            const half2v t23 = tanh_pk_masked(c3[2], c3[3], mkh);
            if (lg < 2) {
                const int base = (w*(TILES_PER_WAVE*16) + t*16 + lr)*10 + lg*4;
                *(half2v*)&obuf[base]     = t01;
                *(half2v*)&obuf[base + 2] = t23;
            }
        }

        // ---- all obuf rows of this chunk written (also drains the prefetch vmcnt)
        __syncthreads();

        // ---- neighbor reduction: 32 points x 8 channels = 256 threads
        {
            const int p  = tid >> 3;   // 0..31
            const int ch = tid & 7;
            float sum = 0.0f;
            #pragma unroll
            for (int i = 0; i < PN; ++i) sum += (float)obuf[(p*PN + i)*10 + ch];
            const int gp = blockIdx.x * (PTS_PER_BLOCK*CHUNKS) + c*PTS_PER_BLOCK + p;
            out[(size_t)ch * NPT + gp] = sum;
        }

        // ---- protect obuf from next chunk's writes
        if (c + 1 < CHUNKS) __syncthreads();
    }
}

extern "C" void kernel_launch(void* const* d_in, const int* in_sizes, int n_in,
                              void* d_out, int out_size, void* d_ws, size_t ws_size,
                              hipStream_t stream) {
    // setup_inputs order: x, grid(unused), freqs, W1, b1, W2, b2, W3, b3
    const float* x     = (const float*)d_in[0];
    const float* freqs = (const float*)d_in[2];
    const float* W1    = (const float*)d_in[3];
    const float* b1    = (const float*)d_in[4];
    const float* W2    = (const float*)d_in[5];
    const float* b2    = (const float*)d_in[6];
    const float* W3    = (const float*)d_in[7];
    const float* b3    = (const float*)d_in[8];
    float* out = (float*)d_out;

    const int grid = NPT / (PTS_PER_BLOCK * CHUNKS);   // 1536 blocks, no remainder
    domino_mfma_kernel<<<grid, 256, 0, stream>>>(x, freqs, W1, b1, W2, b2, W3, b3, out);
}